// Round 1
// baseline (322.354 us; speedup 1.0000x reference)
//
#include <hip/hip_runtime.h>

// Problem constants (from reference): x is (64, 8192, 256) float32, cumsum along dim 1.
#define BATCH 64
#define LEN   8192
#define DIM   256
#define SEGS  32
#define SEGLEN (LEN / SEGS)   // 256 rows per segment
#define D4    (DIM / 4)       // 64 float4 per row

__device__ __forceinline__ void f4_add(float4& a, const float4& v) {
    a.x += v.x; a.y += v.y; a.z += v.z; a.w += v.w;
}

// Pass 1: per-(batch, segment) block (1 wave), lane t owns channels [4t, 4t+3].
// Streams the contiguous 256 KiB segment, reduces to a float4 segment total.
__global__ void seg_sum_kernel(const float* __restrict__ x, float* __restrict__ part) {
    const int s = blockIdx.x;
    const int b = blockIdx.y;
    const int t = threadIdx.x;  // 0..63
    const float4* xp = reinterpret_cast<const float4*>(x)
                     + ((size_t)b * LEN + (size_t)s * SEGLEN) * D4 + t;
    float4 acc = make_float4(0.f, 0.f, 0.f, 0.f);
#pragma unroll 8
    for (int l = 0; l < SEGLEN; ++l) {
        float4 v = xp[(size_t)l * D4];
        f4_add(acc, v);
    }
    reinterpret_cast<float4*>(part)[((size_t)b * SEGS + s) * D4 + t] = acc;
}

// Pass 2: exclusive scan of segment totals along s, per (batch, channel-group).
__global__ void seg_scan_kernel(float* part) {
    const int b = blockIdx.x;
    const int t = threadIdx.x;  // 0..63
    float4* p = reinterpret_cast<float4*>(part) + (size_t)b * SEGS * D4 + t;
    float4 run = make_float4(0.f, 0.f, 0.f, 0.f);
    for (int s = 0; s < SEGS; ++s) {
        float4 v = p[(size_t)s * D4];
        p[(size_t)s * D4] = run;
        f4_add(run, v);
    }
}

// Pass 3: same mapping as pass 1; start from exclusive prefix, emit running cumsum.
__global__ void seg_out_kernel(const float* __restrict__ x,
                               const float* __restrict__ part,
                               float* __restrict__ out) {
    const int s = blockIdx.x;
    const int b = blockIdx.y;
    const int t = threadIdx.x;  // 0..63
    const size_t base = ((size_t)b * LEN + (size_t)s * SEGLEN) * D4 + t;
    const float4* xp = reinterpret_cast<const float4*>(x) + base;
    float4*       op = reinterpret_cast<float4*>(out) + base;
    float4 acc = reinterpret_cast<const float4*>(part)[((size_t)b * SEGS + s) * D4 + t];
#pragma unroll 8
    for (int l = 0; l < SEGLEN; ++l) {
        float4 v = xp[(size_t)l * D4];
        f4_add(acc, v);
        op[(size_t)l * D4] = acc;
    }
}

// Fallback (no workspace needed): one thread per (b, d) chain, serial scan.
__global__ void serial_scan_kernel(const float* __restrict__ x, float* __restrict__ out) {
    const int b = blockIdx.x;
    const int d = threadIdx.x;  // 0..255
    const float* xp = x + (size_t)b * LEN * DIM + d;
    float*       op = out + (size_t)b * LEN * DIM + d;
    float acc = 0.f;
#pragma unroll 8
    for (int l = 0; l < LEN; ++l) {
        acc += xp[(size_t)l * DIM];
        op[(size_t)l * DIM] = acc;
    }
}

extern "C" void kernel_launch(void* const* d_in, const int* in_sizes, int n_in,
                              void* d_out, int out_size, void* d_ws, size_t ws_size,
                              hipStream_t stream) {
    const float* x = (const float*)d_in[0];
    float* out = (float*)d_out;

    const size_t part_bytes = (size_t)BATCH * SEGS * DIM * sizeof(float);  // 2 MiB
    if (ws_size >= part_bytes) {
        float* part = (float*)d_ws;
        seg_sum_kernel<<<dim3(SEGS, BATCH), 64, 0, stream>>>(x, part);
        seg_scan_kernel<<<BATCH, 64, 0, stream>>>(part);
        seg_out_kernel<<<dim3(SEGS, BATCH), 64, 0, stream>>>(x, part, out);
    } else {
        serial_scan_kernel<<<BATCH, DIM, 0, stream>>>(x, out);
    }
}